// Round 1
// 7715.898 us; speedup vs baseline: 3.7875x; 3.7875x over previous
//
#include <hip/hip_runtime.h>
#include <hip/hip_bf16.h>

// ---------------------------------------------------------------------------
// GRU_44513041056013 on MI355X.
//   k_pack_wo : Wo fp32 [1024][32000] -> bf16 packed in MFMA B-fragment order
//   k_embed   : emb gather -> embs bf16 [T][B][E]
//   k_rnn     : persistent kernel, 192 blocks (1/CU), weights LDS-resident.
//               NEW: layer-pipelined 2-phase schedule (layer1 lags 1 superstep)
//               with producer/consumer counters (relaxed poll + single acquire
//               fence) instead of 4-phase full grid barrier with acquire-poll.
//               514 waits instead of 1024 barriers; no per-poll buffer_inv.
//   k_out     : [4096,1024]@[1024,32000] bf16 MFMA GEMM + bias, fp32 out.
// ---------------------------------------------------------------------------

#define B_   16
#define T_   256
#define S_   1024
#define E_   1024
#define K2_  2048
#define V_   32000
#define NBLK 192
#define NTHR 256

typedef __attribute__((ext_vector_type(8))) short bf16x8;
typedef __attribute__((ext_vector_type(4))) float f32x4;

__device__ __forceinline__ unsigned short f2bf(float f) {
  unsigned u = __builtin_bit_cast(unsigned, f);
  unsigned r = (u + 0x7FFFu + ((u >> 16) & 1u)) >> 16;   // RNE
  return (unsigned short)r;
}

// --- Wo packer: slot s = ((ntile*32 + kb)*64 + lane), 8 bf16 per slot.
__global__ void k_pack_wo(const float* __restrict__ Wo,
                          unsigned short* __restrict__ pk) {
  int s = blockIdx.x * 256 + threadIdx.x;          // 2000*32*64 = 4,096,000 slots
  int lane  = s & 63;
  int kb    = (s >> 6) & 31;
  int ntile = s >> 11;
  int n  = ntile * 16 + (lane & 15);
  int k0 = kb * 32 + ((lane >> 4) << 3);
  unsigned short tmp[8];
#pragma unroll
  for (int j = 0; j < 8; j++)
    tmp[j] = f2bf(Wo[(size_t)(k0 + j) * V_ + n]);
  *(bf16x8*)(pk + (size_t)s * 8) = *(bf16x8*)tmp;
}

// --- embedding gather: embs[t][b][e] = bf16(emb[x[b][t]][e])
__global__ void k_embed(const int* __restrict__ x, const float* __restrict__ emb,
                        unsigned short* __restrict__ embs) {
  int i4 = blockIdx.x * 256 + threadIdx.x;
  int e  = (i4 * 4) & (E_ - 1);
  int bt = (i4 * 4) >> 10;                          // t*16 + b
  int b = bt & 15, t = bt >> 4;
  int row = x[b * T_ + t];
  const float* src = emb + (size_t)row * E_ + e;
  unsigned short o[4];
#pragma unroll
  for (int j = 0; j < 4; j++) o[j] = f2bf(src[j]);
  *(unsigned long long*)(embs + (size_t)i4 * 4) = *(unsigned long long*)o;
}

// --- persistent GRU recurrence -------------------------------------------
// Tile ids g=0..383: [z0:0-63 | r0:64-127 | n0:128-191 | z1:192-255 |
// r1:256-319 | n1:320-383]; block bid owns {2bid, 2bid+1} (same matrix).
// Group A (z/r, 128 blocks) and group B (n, 64 blocks) alternate.
// Superstep s (0..256):
//   A: z0,r0 at t=s (s<256); z1,r1 at t=s-1 (s>=1).  waits cntB == 64*s
//   B: n0+h0 at t=s (s<256); n1+h1+hist at t=s-1.    waits cntA == 128*(s+1)
// h0bf parity double-buffered (buf0 = scratch in `out`, buf1 = state region)
// because n0 writes h0(t) while n1 reads h0(t-1) in the same B phase.
__global__ void __launch_bounds__(NTHR, 1) k_rnn(
    const float* __restrict__ Wz, const float* __restrict__ Wr, const float* __restrict__ Wn,
    const float* __restrict__ bz, const float* __restrict__ br, const float* __restrict__ bn,
    const unsigned short* __restrict__ embs,
    float* __restrict__ h0, float* __restrict__ h1,
    unsigned short* __restrict__ h0bf0, unsigned short* __restrict__ h0bf1,
    unsigned short* __restrict__ h1bf,
    unsigned short* __restrict__ rh0bf, unsigned short* __restrict__ rh1bf,
    float* __restrict__ z0buf, float* __restrict__ z1buf,
    unsigned short* __restrict__ hist, unsigned* __restrict__ bar,
    float* __restrict__ htail) {
  extern __shared__ char smem[];
  unsigned short* wlds = (unsigned short*)smem;     // 2 tiles * 32768 ushorts (128 KB)
  float* red = (float*)(smem + 131072);             // 2 tiles * 4 waves * 64 * f32x4 (8 KB)

  const int tid = threadIdx.x, bid = blockIdx.x;
  const int wv = tid >> 6, lane = tid & 63;
  const int q = lane >> 4, m15 = lane & 15;

  const float* WS[3] = {Wz, Wr, Wn};
  const float* BS[3] = {bz, br, bn};
  const int g0 = 2 * bid, g1 = 2 * bid + 1;
  const int mi = g0 >> 6;              // both tiles share mi (g0 even)
  const int mk = mi % 3;               // 0=z 1=r 2=n
  const int layer = mi / 3;
  const int c0a = (g0 & 63) << 4, c0b = (g1 & 63) << 4;

  // Stage my two weight tiles into LDS in MFMA B-fragment order (once).
  for (int ts = 0; ts < 2; ts++) {
    int c0 = ts ? c0b : c0a;
    const float* Wbase = WS[mk] + (size_t)layer * K2_ * S_;
    unsigned short* dst = wlds + ts * 32768;
    for (int k = tid; k < K2_; k += NTHR) {
      const float* srcr = Wbase + (size_t)k * S_ + c0;   // 16 contiguous fp32
      int kb = k >> 5, qq = (k >> 3) & 3, jj = k & 7;
      unsigned short* d2 = dst + kb * 512 + jj;
#pragma unroll
      for (int j16 = 0; j16 < 16; j16++)
        d2[(qq * 16 + j16) * 8] = f2bf(srcr[j16]);
    }
  }
  __syncthreads();

  const bool isA = (mk != 2);
  unsigned* myCnt  = bar + (isA ? 0 : 32);    // 128B apart
  unsigned* othCnt = bar + (isA ? 32 : 0);

  for (int s = 0; s <= T_; s++) {
    // --- wait for the other group (relaxed poll, acquire fence on exit) ---
    if (tid == 0) {
      unsigned tgt = isA ? (unsigned)(64u * (unsigned)s)
                         : (unsigned)(128u * (unsigned)(s + 1));
      unsigned spins = 0;
      while (__hip_atomic_load(othCnt, __ATOMIC_RELAXED, __HIP_MEMORY_SCOPE_AGENT) < tgt) {
        __builtin_amdgcn_s_sleep(1);
        if ((++spins & 255u) == 0u)   // safety valve vs stale cached line
          (void)__hip_atomic_load(othCnt, __ATOMIC_ACQUIRE, __HIP_MEMORY_SCOPE_AGENT);
      }
      __builtin_amdgcn_fence(__ATOMIC_ACQUIRE, "agent");
    }
    __syncthreads();

    const int t = layer ? (s - 1) : s;
    if (t >= 0 && t < T_) {
      const unsigned short* embt   = embs + (size_t)t * B_ * E_;
      const unsigned short* h0prev = ((t - 1) & 1) ? h0bf1 : h0bf0;  // h0(t-1)
      const unsigned short* h0cur  = (t & 1) ? h0bf1 : h0bf0;        // h0(t)
      const unsigned short *AL, *AR;
      if (layer == 0) { AL = embt;  AR = isA ? h0prev : rh0bf; }
      else            { AL = h0cur; AR = isA ? h1bf   : rh1bf; }

      // Both tiles share A-fragments: one A load feeds two MFMA chains.
      f32x4 acc0 = {0.f, 0.f, 0.f, 0.f}, acc1 = {0.f, 0.f, 0.f, 0.f};
#pragma unroll
      for (int i = 0; i < 16; i++) {
        int kb = wv * 16 + i;
        int k0 = kb * 32;
        const unsigned short* ab = (k0 < 1024)
            ? (AL + m15 * 1024 + k0 + q * 8)
            : (AR + m15 * 1024 + (k0 - 1024) + q * 8);
        bf16x8 av = *(const bf16x8*)ab;
        bf16x8 b0 = *(const bf16x8*)(wlds + kb * 512 + lane * 8);
        bf16x8 b1 = *(const bf16x8*)(wlds + 32768 + kb * 512 + lane * 8);
        acc0 = __builtin_amdgcn_mfma_f32_16x16x32_bf16(av, b0, acc0, 0, 0, 0);
        acc1 = __builtin_amdgcn_mfma_f32_16x16x32_bf16(av, b1, acc1, 0, 0, 0);
      }
      *(f32x4*)(red + (wv * 64 + lane) * 4) = acc0;
      *(f32x4*)(red + (256 + wv * 64 + lane) * 4) = acc1;
      __syncthreads();
      if (wv < 2) {                      // wave0 -> tile0, wave1 -> tile1
        const float* rb = red + (wv * 256 + lane) * 4;
        f32x4 a0 = *(const f32x4*)(rb);
        f32x4 a1 = *(const f32x4*)(rb + 64 * 4);
        f32x4 a2 = *(const f32x4*)(rb + 128 * 4);
        f32x4 a3 = *(const f32x4*)(rb + 192 * 4);
        f32x4 sm = a0 + a1 + a2 + a3;
        int c = (wv ? c0b : c0a) + m15;
        float bias = BS[mk][layer * S_ + c];
        float* hm = layer ? h1 : h0;
        unsigned short* hwr = layer ? h1bf : ((t & 1) ? h0bf1 : h0bf0);
#pragma unroll
        for (int r = 0; r < 4; r++) {
          int m = q * 4 + r;             // D row = (lane>>4)*4 + reg
          float p = sm[r] + bias;
          int idx = m * S_ + c;
          if (mk == 0) {                 // z gate
            float zv = 1.f / (1.f + __expf(-p));
            (layer ? z1buf : z0buf)[idx] = zv;
          } else if (mk == 1) {          // r gate -> r*h (bf16 A input for n)
            float rv = 1.f / (1.f + __expf(-p));
            (layer ? rh1bf : rh0bf)[idx] = f2bf(rv * hm[idx]);
          } else {                       // n -> h update
            float nv = tanhf(p);
            float zv = (layer ? z1buf : z0buf)[idx];
            float hv = hm[idx];
            float hn = (1.f - zv) * hv + zv * nv;
            hm[idx] = hn;                // fp32 master state
            unsigned short hb = f2bf(hn);
            hwr[idx] = hb;
            if (layer) hist[(size_t)t * B_ * S_ + idx] = hb;
          }
        }
      }
      __syncthreads();
    }

    // --- signal: release-RMW (wbl2 folded into the atomic) ---
    if (tid == 0)
      __hip_atomic_fetch_add(myCnt, 1u, __ATOMIC_RELEASE, __HIP_MEMORY_SCOPE_AGENT);
  }

  // everyone waits for B's final superstep, then copy h_final tail
  if (tid == 0) {
    unsigned spins = 0;
    while (__hip_atomic_load(bar + 32, __ATOMIC_RELAXED, __HIP_MEMORY_SCOPE_AGENT) <
           64u * 257u) {
      __builtin_amdgcn_s_sleep(1);
      if ((++spins & 255u) == 0u)
        (void)__hip_atomic_load(bar + 32, __ATOMIC_ACQUIRE, __HIP_MEMORY_SCOPE_AGENT);
    }
    __builtin_amdgcn_fence(__ATOMIC_ACQUIRE, "agent");
  }
  __syncthreads();
  for (int i = bid * NTHR + tid; i < 2 * B_ * S_; i += NBLK * NTHR) {
    int ly = i >> 14, rem = i & 16383;
    htail[i] = (ly ? h1 : h0)[rem];
  }
}

// --- output projection: C[4096][32000] = hist @ Wo + bo, fp32 out ---------
__global__ void __launch_bounds__(256) k_out(
    const unsigned short* __restrict__ hist, const unsigned short* __restrict__ pk,
    const float* __restrict__ bo, float* __restrict__ out) {
  int blk = blockIdx.x;
  int mt = blk & 31;                 // m fast -> 32 consecutive blocks share B (L2)
  int nt = blk >> 5;
  int wv = threadIdx.x >> 6, lane = threadIdx.x & 63;
  int wm = wv & 1, wn = wv >> 1;
  int m0 = mt * 128 + wm * 64;
  int n0 = nt * 128 + wn * 64;
  int q = lane >> 4, m15 = lane & 15;

  f32x4 zero = {0.f, 0.f, 0.f, 0.f};
  f32x4 acc[4][4];
#pragma unroll
  for (int i = 0; i < 4; i++)
#pragma unroll
    for (int j = 0; j < 4; j++) acc[i][j] = zero;

#pragma unroll 2
  for (int kb = 0; kb < 32; kb++) {
    bf16x8 a[4], b[4];
#pragma unroll
    for (int i = 0; i < 4; i++)
      a[i] = *(const bf16x8*)(hist + (size_t)(m0 + i * 16 + m15) * 1024 + kb * 32 + q * 8);
#pragma unroll
    for (int j = 0; j < 4; j++) {
      int nt16 = (n0 >> 4) + j;
      b[j] = *(const bf16x8*)(pk + ((size_t)(nt16 * 32 + kb) * 64 + lane) * 8);
    }
#pragma unroll
    for (int i = 0; i < 4; i++)
#pragma unroll
      for (int j = 0; j < 4; j++)
        acc[i][j] = __builtin_amdgcn_mfma_f32_16x16x32_bf16(a[i], b[j], acc[i][j], 0, 0, 0);
  }
#pragma unroll
  for (int i = 0; i < 4; i++) {
    int mbase = m0 + i * 16 + q * 4;
#pragma unroll
    for (int r = 0; r < 4; r++) {
      int m = mbase + r;
      int tt = m >> 4, bb = m & 15;
      float* orow = out + ((size_t)(bb * T_ + tt)) * V_;   // out[b][t][:]
#pragma unroll
      for (int j = 0; j < 4; j++) {
        int n = n0 + j * 16 + m15;
        orow[n] = acc[i][j][r] + bo[n];
      }
    }
  }
}

extern "C" void kernel_launch(void* const* d_in, const int* in_sizes, int n_in,
                              void* d_out, int out_size, void* d_ws, size_t ws_size,
                              hipStream_t stream) {
  const int*   x   = (const int*)d_in[0];
  const float* emb = (const float*)d_in[1];
  const float* Wz  = (const float*)d_in[2];
  const float* bz  = (const float*)d_in[3];
  const float* Wr  = (const float*)d_in[4];
  const float* br  = (const float*)d_in[5];
  const float* Wn  = (const float*)d_in[6];
  const float* bn  = (const float*)d_in[7];
  const float* Wo  = (const float*)d_in[8];
  const float* bo  = (const float*)d_in[9];
  float* out = (float*)d_out;

  // ws layout (bytes): pk 65,536,000 | embs 8,388,608 | hist 8,388,608 | state 393,472
  char* ws = (char*)d_ws;
  unsigned short* pk   = (unsigned short*)(ws);
  unsigned short* embs = (unsigned short*)(ws + 65536000);
  unsigned short* hist = (unsigned short*)(ws + 65536000 + 8388608);
  char* st = ws + 65536000 + 2 * 8388608;
  float* h0            = (float*)(st);
  float* h1            = (float*)(st + 65536);
  unsigned short* h0bf1= (unsigned short*)(st + 131072);   // h0 parity-1 buffer (zeroed)
  unsigned short* h1bf = (unsigned short*)(st + 163840);
  unsigned short* rh0bf= (unsigned short*)(st + 196608);
  unsigned short* rh1bf= (unsigned short*)(st + 229376);
  float* z0buf         = (float*)(st + 262144);
  float* z1buf         = (float*)(st + 327680);
  unsigned* bar        = (unsigned*)(st + 393216);         // cntA @+0, cntB @+128B
  // h0 parity-0 buffer: first 32KB of out (written t=0 before any read;
  // k_out fully overwrites out afterwards)
  unsigned short* h0bf0 = (unsigned short*)out;

  // state + barrier counters must be zero every launch (ws is re-poisoned)
  hipMemsetAsync(st, 0, 393216 + 256, stream);
  k_pack_wo<<<16000, 256, 0, stream>>>(Wo, pk);
  k_embed<<<4096, 256, 0, stream>>>(x, emb, embs);
  (void)hipFuncSetAttribute((const void*)k_rnn,
                            hipFuncAttributeMaxDynamicSharedMemorySize, 139264);
  k_rnn<<<NBLK, NTHR, 139264, stream>>>(Wz, Wr, Wn, bz, br, bn, embs,
                                        h0, h1, h0bf0, h0bf1, h1bf, rh0bf, rh1bf,
                                        z0buf, z1buf, hist, bar,
                                        out + 131072000LL);
  k_out<<<8000, 256, 0, stream>>>(hist, pk, bo, out);
}